// Round 17
// baseline (375.085 us; speedup 1.0000x reference)
//
#include <hip/hip_runtime.h>

typedef __attribute__((ext_vector_type(8)))  short bf16x8;
typedef __attribute__((ext_vector_type(16))) float f32x16;
typedef __attribute__((ext_vector_type(2)))  float f32x2;

#define KNBR 32
#define WAVES 8         // waves per block (512 threads)
#define GQ   2          // queries per wave, gather-compute pipelined

union Frag { int4 i; bf16x8 b; };

__device__ __forceinline__ unsigned short f2bf(float f) {
    unsigned u = __float_as_uint(f);
    u += 0x7FFFu + ((u >> 16) & 1u);          // RNE to bf16
    return (unsigned short)(u >> 16);
}

__device__ __forceinline__ unsigned cvt_pk_bf16(float lo, float hi) {
    unsigned r;
    asm("v_cvt_pk_bf16_f32 %0, %1, %2" : "=v"(r) : "v"(lo), "v"(hi));
    return r;
}

// gelu_tanh(v) = v * sigmoid(2*c0*(v + c1 v^3)), 2-wide packed (v_pk_* fp32);
// only exp/rcp are scalar trans ops.
__device__ __forceinline__ f32x2 fast_gelu2(f32x2 v) {
    const f32x2 c1v  = {0.044715f, 0.044715f};
    const f32x2 onev = {1.0f, 1.0f};
    const f32x2 K2v  = {-2.3022081951f, -2.3022081951f};  // -2*sqrt(2/pi)*log2(e)
    f32x2 p = v * __builtin_elementwise_fma(c1v, v * v, onev);
    f32x2 t = K2v * p;
    float e0, e1, r0, r1;
    asm("v_exp_f32 %0, %1" : "=v"(e0) : "v"(t.x));
    asm("v_exp_f32 %0, %1" : "=v"(e1) : "v"(t.y));
    f32x2 ev = {e0, e1};
    f32x2 d = ev + onev;
    asm("v_rcp_f32 %0, %1" : "=v"(r0) : "v"(d.x));
    asm("v_rcp_f32 %0, %1" : "=v"(r1) : "v"(d.y));
    f32x2 rv = {r0, r1};
    return v * rv;
}

// 32x32x16 fragment maps (A: row=l&31, B: col=l&31, k=(l>>5)*8+e per K-step).
// C/D: col=lane&31, row=(reg&3)+8*(reg>>2)+4*(lane>>5)  [verified r15].
// GEMM1 slot map (K padded 70->80): 0..63 f_y; 64..69 coords; 70 BIAS; rest 0.
// GEMM2 slot map = identity on h's C/D register layout.
__global__ __launch_bounds__(256) void pack_weights_kernel(
    const float* __restrict__ W1, const float* __restrict__ W2,
    const float* __restrict__ b1, const float* __restrict__ av,
    int4* __restrict__ W1p, int4* __restrict__ W2p, float* __restrict__ avp)
{
    const int idx = blockIdx.x * 256 + threadIdx.x;
    unsigned short vals[8];
    if (idx < 1280) {                      // W1 A-frags: 20 regions x 64 lanes
        const int a = idx >> 6, l = idx & 63;
        const int Mt = a / 5, ks = a - Mt * 5;
        const int row = Mt * 32 + (l & 31), hi = l >> 5;
        #pragma unroll
        for (int e = 0; e < 8; ++e) {
            const int slot = ks * 16 + hi * 8 + e;
            float f;
            if      (slot < 64)  f = W1[(slot + 6) * 128 + row];
            else if (slot < 70)  f = W1[(slot - 64) * 128 + row];
            else if (slot == 70) f = b1[row];
            else                 f = 0.0f;
            vals[e] = f2bf(f);
        }
        int4 v;
        v.x = vals[0] | (vals[1] << 16); v.y = vals[2] | (vals[3] << 16);
        v.z = vals[4] | (vals[5] << 16); v.w = vals[6] | (vals[7] << 16);
        W1p[idx] = v;
    } else if (idx < 2304) {               // W2 B-frags: 16 regions x 64 lanes
        const int i2 = idx - 1280;
        const int rgn = i2 >> 6, l = i2 & 63;
        const int Nt = rgn >> 3, ks2 = rgn & 7;
        const int col = Nt * 32 + (l & 31), hi = l >> 5;
        #pragma unroll
        for (int e = 0; e < 8; ++e) {
            const int Mt = ks2 >> 1;
            const int t  = 2 * (ks2 & 1) + (e >> 2);
            const int c  = e & 3;
            const int hid = Mt * 32 + 4 * (2 * t + hi) + c;
            vals[e] = f2bf(W2[hid * 64 + col]);
        }
        int4 v;
        v.x = vals[0] | (vals[1] << 16); v.y = vals[2] | (vals[3] << 16);
        v.z = vals[4] | (vals[5] << 16); v.w = vals[6] | (vals[7] << 16);
        W2p[i2] = v;
    } else if (idx < 2432) {               // av repacked into C/D reg order
        const int r_ = idx - 2304;         // [Mt][hi][r]
        const int Mt = r_ >> 5, hi = (r_ >> 4) & 1, r = r_ & 15;
        avp[r_] = av[Mt * 32 + 8 * (r >> 2) + 4 * hi + (r & 3)];
    }
}

// phase 2+3: GEMM1 + packed gelu + score partial + A2 pack
__device__ __forceinline__ void gemm1_part(
    const Frag (&B1)[5], const int4* __restrict__ sW1,
    const float* __restrict__ sAv, int l, int hi,
    Frag (&A2)[8], float& sc_out)
{
    const f32x16 z16 = {0.f,0.f,0.f,0.f,0.f,0.f,0.f,0.f,
                        0.f,0.f,0.f,0.f,0.f,0.f,0.f,0.f};
    f32x2 scv = {0.f, 0.f};
    #pragma unroll
    for (int p = 0; p < 2; ++p) {
        f32x16 aA = z16, aB = z16;
        #pragma unroll
        for (int ks = 0; ks < 5; ++ks) {
            Frag wa0, wa1;
            wa0.i = sW1[((2 * p + 0) * 5 + ks) * 64 + l];
            wa1.i = sW1[((2 * p + 1) * 5 + ks) * 64 + l];
            aA = __builtin_amdgcn_mfma_f32_32x32x16_bf16(wa0.b, B1[ks].b, aA, 0, 0, 0);
            aB = __builtin_amdgcn_mfma_f32_32x32x16_bf16(wa1.b, B1[ks].b, aB, 0, 0, 0);
        }
        #pragma unroll
        for (int m = 0; m < 2; ++m) {
            const f32x16 ac = m ? aB : aA;
            const int Mt = 2 * p + m;
            const float* avb = sAv + Mt * 32 + hi * 16;
            float4 av0 = *(const float4*)(avb + 0);
            float4 av1 = *(const float4*)(avb + 4);
            float4 av2 = *(const float4*)(avb + 8);
            float4 av3 = *(const float4*)(avb + 12);
            f32x2 avv[8] = {{av0.x, av0.y}, {av0.z, av0.w},
                            {av1.x, av1.y}, {av1.z, av1.w},
                            {av2.x, av2.y}, {av2.z, av2.w},
                            {av3.x, av3.y}, {av3.z, av3.w}};
            unsigned hw[8];
            #pragma unroll
            for (int i = 0; i < 8; ++i) {
                f32x2 vin = {ac[2 * i], ac[2 * i + 1]};
                f32x2 hv = fast_gelu2(vin);
                scv = __builtin_elementwise_fma(hv, avv[i], scv);
                hw[i] = cvt_pk_bf16(hv.x, hv.y);
            }
            A2[2 * Mt + 0].i.x = hw[0];
            A2[2 * Mt + 0].i.y = hw[1];
            A2[2 * Mt + 0].i.z = hw[2];
            A2[2 * Mt + 0].i.w = hw[3];
            A2[2 * Mt + 1].i.x = hw[4];
            A2[2 * Mt + 1].i.y = hw[5];
            A2[2 * Mt + 1].i.z = hw[6];
            A2[2 * Mt + 1].i.w = hw[7];
        }
    }
    sc_out = scv.x + scv.y;
}

// phases 4-6: softmax, GEMM2, alpha-weighted reduce + store
__device__ __forceinline__ void finish_query(
    const Frag (&A2)[8], float sc, const int4* __restrict__ sW2,
    const float* __restrict__ b2, float* __restrict__ out,
    int qc, bool do_store, int l, int hi)
{
    const f32x16 z16 = {0.f,0.f,0.f,0.f,0.f,0.f,0.f,0.f,
                        0.f,0.f,0.f,0.f,0.f,0.f,0.f,0.f};
    sc += __shfl_xor(sc, 32, 64);          // sum over lane halves
    float mx = sc;
    mx = fmaxf(mx, __shfl_xor(mx, 1, 64));
    mx = fmaxf(mx, __shfl_xor(mx, 2, 64));
    mx = fmaxf(mx, __shfl_xor(mx, 4, 64));
    mx = fmaxf(mx, __shfl_xor(mx, 8, 64));
    mx = fmaxf(mx, __shfl_xor(mx, 16, 64));
    float ex = __expf(sc - mx);
    float sm = ex;
    sm += __shfl_xor(sm, 1, 64);
    sm += __shfl_xor(sm, 2, 64);
    sm += __shfl_xor(sm, 4, 64);
    sm += __shfl_xor(sm, 8, 64);
    sm += __shfl_xor(sm, 16, 64);
    const float alpha = __fdividef(ex, sm);    // alpha[edge l&31]

    f32x16 o0 = z16, o1 = z16;
    #pragma unroll
    for (int ks2 = 0; ks2 < 8; ++ks2) {
        Frag w0, w1;
        w0.i = sW2[(0 * 8 + ks2) * 64 + l];
        w1.i = sW2[(1 * 8 + ks2) * 64 + l];
        o0 = __builtin_amdgcn_mfma_f32_32x32x16_bf16(A2[ks2].b, w0.b, o0, 0, 0, 0);
        o1 = __builtin_amdgcn_mfma_f32_32x32x16_bf16(A2[ks2].b, w1.b, o1, 0, 0, 0);
    }

    float ar[16];
    #pragma unroll
    for (int r = 0; r < 16; ++r)
        ar[r] = __shfl(alpha, 8 * (r >> 2) + 4 * hi + (r & 3), 64);

    #pragma unroll
    for (int nt = 0; nt < 2; ++nt) {
        const f32x16 oo = nt ? o1 : o0;
        f32x2 acc = {0.f, 0.f};
        #pragma unroll
        for (int i = 0; i < 8; ++i) {
            f32x2 ov = {oo[2 * i], oo[2 * i + 1]};
            f32x2 av2 = {ar[2 * i], ar[2 * i + 1]};
            acc = __builtin_elementwise_fma(ov, av2, acc);
        }
        float o = acc.x + acc.y;
        o += __shfl_xor(o, 32, 64);
        if (do_store && l < 32)
            out[qc * 64 + nt * 32 + l] = o + b2[nt * 32 + l];
    }
}

__device__ __forceinline__ void build_B1(
    Frag (&B1)[5],
    float4 u0, float4 u1, float4 u2, float4 u3,
    float4 u4, float4 u5, float4 u6, float4 u7,
    float2 y01, float yz, float2 x01, float xz, int hi)
{
    B1[0].i.x = cvt_pk_bf16(u0.x, u0.y); B1[0].i.y = cvt_pk_bf16(u0.z, u0.w);
    B1[0].i.z = cvt_pk_bf16(u1.x, u1.y); B1[0].i.w = cvt_pk_bf16(u1.z, u1.w);
    B1[1].i.x = cvt_pk_bf16(u2.x, u2.y); B1[1].i.y = cvt_pk_bf16(u2.z, u2.w);
    B1[1].i.z = cvt_pk_bf16(u3.x, u3.y); B1[1].i.w = cvt_pk_bf16(u3.z, u3.w);
    B1[2].i.x = cvt_pk_bf16(u4.x, u4.y); B1[2].i.y = cvt_pk_bf16(u4.z, u4.w);
    B1[2].i.z = cvt_pk_bf16(u5.x, u5.y); B1[2].i.w = cvt_pk_bf16(u5.z, u5.w);
    B1[3].i.x = cvt_pk_bf16(u6.x, u6.y); B1[3].i.y = cvt_pk_bf16(u6.z, u6.w);
    B1[3].i.z = cvt_pk_bf16(u7.x, u7.y); B1[3].i.w = cvt_pk_bf16(u7.z, u7.w);
    B1[4].i = make_int4(0, 0, 0, 0);
    if (hi == 0) {
        B1[4].i.x = cvt_pk_bf16(y01.x, y01.y);
        B1[4].i.y = cvt_pk_bf16(yz,    x01.x);
        B1[4].i.z = cvt_pk_bf16(x01.y, xz);
        B1[4].i.w = cvt_pk_bf16(1.0f,  0.0f);   // slot 70 = bias edge value
    }
}

__global__ __launch_bounds__(512, 4) void it_mfma_kernel(
    const float* __restrict__ y,     // [n_in][3]
    const float* __restrict__ xq,    // [n_out][3]
    const float* __restrict__ f_y,   // [n_in][64]
    const float* __restrict__ b2,    // [64]
    const int*   __restrict__ nbr,   // [n_out*32]
    const int4*  __restrict__ Wall,  // W1p(1280) ++ W2p(1024) ++ avp(128 f32)
    float*       __restrict__ out,   // [n_out][64]
    int n_out)
{
    __shared__ int4  sW[2304];             // 36 KB: W1 frags then W2 frags
    __shared__ float sAv[128];             // av in C/D register order

    const int tid = threadIdx.x;
    const int w   = tid >> 6;              // wave 0..7
    const int l   = tid & 63;              // lane
    const int el  = l & 31;                // this lane's edge
    const int hi  = l >> 5;                // lane half

    const int qa = blockIdx.x * (WAVES * GQ) + w;          // query 0 of wave
    const int qb = qa + WAVES;                             // query 1 of wave
    const bool act_a = (qa < n_out);
    const bool act_b = (qb < n_out);
    const int qca = act_a ? qa : 0;
    const int qcb = act_b ? qb : 0;

    // both nbr loads first: dependent f_y chains start ASAP
    const int ni_a = nbr[qca * KNBR + el];
    const int ni_b = nbr[qcb * KNBR + el];

    // ---- prologue: stage fragments + av into LDS ----
    #pragma unroll
    for (int t = 0; t < 5; ++t) {
        const int idx = tid + t * 512;
        if (idx < 2304) sW[idx] = Wall[idx];
    }
    if (tid < 128) sAv[tid] = ((const float*)(Wall + 2304))[tid];

    // ---- query-a gather issues BEFORE the barrier: hides under staging ----
    const float4* fa = (const float4*)(f_y + (long)ni_a * 64);
    float4 a0 = fa[ 0 + 2 * hi], a1 = fa[ 1 + 2 * hi];
    float4 a2 = fa[ 4 + 2 * hi], a3 = fa[ 5 + 2 * hi];
    float4 a4 = fa[ 8 + 2 * hi], a5 = fa[ 9 + 2 * hi];
    float4 a6 = fa[12 + 2 * hi], a7 = fa[13 + 2 * hi];
    float2 ya01 = {0.f, 0.f}, xa01 = {0.f, 0.f};
    float  yaz = 0.f, xaz = 0.f;
    if (hi == 0) {
        ya01 = *(const float2*)(y + ni_a * 3);
        yaz  = y[ni_a * 3 + 2];
        xa01 = *(const float2*)(xq + qca * 3);
        xaz  = xq[qca * 3 + 2];
    }
    __syncthreads();
    const int4* sW1 = sW;                  // region (Mt*5+ks)*64 + lane
    const int4* sW2 = sW + 1280;           // region (Nt*8+ks2)*64 + lane

    if (!act_a) return;                    // after the only barrier: safe

    // ---- query a: build B1, GEMM1 ----
    Frag B1a[5];
    build_B1(B1a, a0, a1, a2, a3, a4, a5, a6, a7, ya01, yaz, xa01, xaz, hi);
    Frag A2a[8];
    float sca;
    gemm1_part(B1a, sW1, sAv, l, hi, A2a, sca);

    // ---- issue query-b gather: lands under a's softmax+GEMM2+store ----
    const float4* fb = (const float4*)(f_y + (long)ni_b * 64);
    float4 c0 = fb[ 0 + 2 * hi], c1 = fb[ 1 + 2 * hi];
    float4 c2 = fb[ 4 + 2 * hi], c3 = fb[ 5 + 2 * hi];
    float4 c4 = fb[ 8 + 2 * hi], c5 = fb[ 9 + 2 * hi];
    float4 c6 = fb[12 + 2 * hi], c7 = fb[13 + 2 * hi];
    float2 yb01 = {0.f, 0.f}, xb01 = {0.f, 0.f};
    float  ybz = 0.f, xbz = 0.f;
    if (hi == 0) {
        yb01 = *(const float2*)(y + ni_b * 3);
        ybz  = y[ni_b * 3 + 2];
        xb01 = *(const float2*)(xq + qcb * 3);
        xbz  = xq[qcb * 3 + 2];
    }

    // ---- query a: softmax + GEMM2 + store ----
    finish_query(A2a, sca, sW2, b2, out, qca, true, l, hi);

    // ---- query b: loads have landed; compute with no gather stall ----
    Frag B1b[5];
    build_B1(B1b, c0, c1, c2, c3, c4, c5, c6, c7, yb01, ybz, xb01, xbz, hi);
    Frag A2b[8];
    float scb;
    gemm1_part(B1b, sW1, sAv, l, hi, A2b, scb);
    finish_query(A2b, scb, sW2, b2, out, qcb, act_b, l, hi);
}

extern "C" void kernel_launch(void* const* d_in, const int* in_sizes, int n_in,
                              void* d_out, int out_size, void* d_ws, size_t ws_size,
                              hipStream_t stream) {
    const float* y   = (const float*)d_in[0];
    const float* xq  = (const float*)d_in[1];
    const float* f_y = (const float*)d_in[2];
    const float* W1  = (const float*)d_in[3];
    const float* b1  = (const float*)d_in[4];
    const float* W2  = (const float*)d_in[5];
    const float* b2  = (const float*)d_in[6];
    const float* av  = (const float*)d_in[7];
    const int*   nbr = (const int*)d_in[8];
    float* out = (float*)d_out;

    const int n_out = in_sizes[1] / 3;      // x is [n_out][3]

    int4*  W1p = (int4*)d_ws;               // 1280 frags = 20 KB
    int4*  W2p = W1p + 1280;                // 1024 frags = 16 KB
    float* avp = (float*)(W1p + 2304);      // 128 floats

    pack_weights_kernel<<<10, 256, 0, stream>>>(W1, W2, b1, av, W1p, W2p, avp);
    const int qpb = WAVES * GQ;             // 16 queries per block
    const int nblk = (n_out + qpb - 1) / qpb;
    it_mfma_kernel<<<nblk, 512, 0, stream>>>(y, xq, f_y, b2, nbr,
                                             W1p, out, n_out);
}

// Round 18
// 70.694 us; speedup vs baseline: 5.3057x; 5.3057x over previous
//
#include <hip/hip_runtime.h>

typedef __attribute__((ext_vector_type(8)))  short bf16x8;
typedef __attribute__((ext_vector_type(16))) float f32x16;
typedef __attribute__((ext_vector_type(2)))  float f32x2;

#define KNBR 32
#define WAVES 8         // waves per block, one query per wave (512 threads)

union Frag { int4 i; bf16x8 b; };

__device__ __forceinline__ unsigned short f2bf(float f) {
    unsigned u = __float_as_uint(f);
    u += 0x7FFFu + ((u >> 16) & 1u);          // RNE to bf16
    return (unsigned short)(u >> 16);
}

__device__ __forceinline__ unsigned cvt_pk_bf16(float lo, float hi) {
    unsigned r;
    asm("v_cvt_pk_bf16_f32 %0, %1, %2" : "=v"(r) : "v"(lo), "v"(hi));
    return r;
}

// gelu_tanh(v) = v * sigmoid(2*c0*(v + c1 v^3)), 2-wide packed (v_pk_* fp32);
// only exp/rcp are scalar trans ops.
__device__ __forceinline__ f32x2 fast_gelu2(f32x2 v) {
    const f32x2 c1v  = {0.044715f, 0.044715f};
    const f32x2 onev = {1.0f, 1.0f};
    const f32x2 K2v  = {-2.3022081951f, -2.3022081951f};  // -2*sqrt(2/pi)*log2(e)
    f32x2 p = v * __builtin_elementwise_fma(c1v, v * v, onev);
    f32x2 t = K2v * p;
    float e0, e1, r0, r1;
    asm("v_exp_f32 %0, %1" : "=v"(e0) : "v"(t.x));
    asm("v_exp_f32 %0, %1" : "=v"(e1) : "v"(t.y));
    f32x2 ev = {e0, e1};
    f32x2 d = ev + onev;
    asm("v_rcp_f32 %0, %1" : "=v"(r0) : "v"(d.x));
    asm("v_rcp_f32 %0, %1" : "=v"(r1) : "v"(d.y));
    f32x2 rv = {r0, r1};
    return v * rv;
}

// 32x32x16 fragment maps (A: row=l&31, B: col=l&31, k=(l>>5)*8+e per K-step).
// C/D: col=lane&31, row=(reg&3)+8*(reg>>2)+4*(lane>>5)  [verified r15].
// GEMM1 slot map (K padded 70->80): 0..63 f_y; 64..69 coords; 70 BIAS; rest 0.
// GEMM2 slot map = identity on h's C/D register layout.
__global__ __launch_bounds__(256) void pack_weights_kernel(
    const float* __restrict__ W1, const float* __restrict__ W2,
    const float* __restrict__ b1, const float* __restrict__ av,
    int4* __restrict__ W1p, int4* __restrict__ W2p, float* __restrict__ avp)
{
    const int idx = blockIdx.x * 256 + threadIdx.x;
    unsigned short vals[8];
    if (idx < 1280) {                      // W1 A-frags: 20 regions x 64 lanes
        const int a = idx >> 6, l = idx & 63;
        const int Mt = a / 5, ks = a - Mt * 5;
        const int row = Mt * 32 + (l & 31), hi = l >> 5;
        #pragma unroll
        for (int e = 0; e < 8; ++e) {
            const int slot = ks * 16 + hi * 8 + e;
            float f;
            if      (slot < 64)  f = W1[(slot + 6) * 128 + row];
            else if (slot < 70)  f = W1[(slot - 64) * 128 + row];
            else if (slot == 70) f = b1[row];
            else                 f = 0.0f;
            vals[e] = f2bf(f);
        }
        int4 v;
        v.x = vals[0] | (vals[1] << 16); v.y = vals[2] | (vals[3] << 16);
        v.z = vals[4] | (vals[5] << 16); v.w = vals[6] | (vals[7] << 16);
        W1p[idx] = v;
    } else if (idx < 2304) {               // W2 B-frags: 16 regions x 64 lanes
        const int i2 = idx - 1280;
        const int rgn = i2 >> 6, l = i2 & 63;
        const int Nt = rgn >> 3, ks2 = rgn & 7;
        const int col = Nt * 32 + (l & 31), hi = l >> 5;
        #pragma unroll
        for (int e = 0; e < 8; ++e) {
            const int Mt = ks2 >> 1;
            const int t  = 2 * (ks2 & 1) + (e >> 2);
            const int c  = e & 3;
            const int hid = Mt * 32 + 4 * (2 * t + hi) + c;
            vals[e] = f2bf(W2[hid * 64 + col]);
        }
        int4 v;
        v.x = vals[0] | (vals[1] << 16); v.y = vals[2] | (vals[3] << 16);
        v.z = vals[4] | (vals[5] << 16); v.w = vals[6] | (vals[7] << 16);
        W2p[i2] = v;
    } else if (idx < 2432) {               // av repacked into C/D reg order
        const int r_ = idx - 2304;         // [Mt][hi][r]
        const int Mt = r_ >> 5, hi = (r_ >> 4) & 1, r = r_ & 15;
        avp[r_] = av[Mt * 32 + 8 * (r >> 2) + 4 * hi + (r & 3)];
    }
}

__global__ __launch_bounds__(512, 4) void it_mfma_kernel(
    const float* __restrict__ y,     // [n_in][3]
    const float* __restrict__ xq,    // [n_out][3]
    const float* __restrict__ f_y,   // [n_in][64]
    const float* __restrict__ b2,    // [64]
    const int*   __restrict__ nbr,   // [n_out*32]
    const int4*  __restrict__ Wall,  // W1p(1280) ++ W2p(1024) ++ avp(128 f32)
    float*       __restrict__ out,   // [n_out][64]
    int n_out)
{
    __shared__ int4  sW[2304];             // 36 KB: W1 frags then W2 frags
    __shared__ float sAv[128];             // av in C/D register order

    const int tid = threadIdx.x;
    const int w   = tid >> 6;              // wave 0..7
    const int l   = tid & 63;              // lane
    const int el  = l & 31;                // this lane's edge
    const int hi  = l >> 5;                // lane half

    const int q = blockIdx.x * WAVES + w;
    const bool active = (q < n_out);
    const int qc = active ? q : 0;

    // nbr first: its latency hides under the (independent) staging loads
    const int ni = nbr[qc * KNBR + el];

    // ---- stage fragments + av into LDS (issues immediately) ----
    #pragma unroll
    for (int t = 0; t < 5; ++t) {
        const int idx = tid + t * 512;
        if (idx < 2304) sW[idx] = Wall[idx];
    }
    if (tid < 128) sAv[tid] = ((const float*)(Wall + 2304))[tid];

    // ---- f_y + coord gather issues BEFORE the barrier: latency hides under
    //      staging + barrier drain instead of heading the compute chain ----
    const float4* fb = (const float4*)(f_y + (long)ni * 64);
    float4 u0 = fb[ 0 + 2 * hi], u1 = fb[ 1 + 2 * hi];
    float4 u2 = fb[ 4 + 2 * hi], u3 = fb[ 5 + 2 * hi];
    float4 u4 = fb[ 8 + 2 * hi], u5 = fb[ 9 + 2 * hi];
    float4 u6 = fb[12 + 2 * hi], u7 = fb[13 + 2 * hi];
    float2 y01 = {0.f, 0.f}, x01 = {0.f, 0.f};
    float  yz = 0.f, xz = 0.f;
    if (hi == 0) {
        y01 = *(const float2*)(y + ni * 3);
        yz  = y[ni * 3 + 2];
        x01 = *(const float2*)(xq + qc * 3);
        xz  = xq[qc * 3 + 2];
    }
    __syncthreads();
    const int4* sW1 = sW;                  // region (Mt*5+ks)*64 + lane
    const int4* sW2 = sW + 1280;           // region (Nt*8+ks2)*64 + lane

    if (!active) return;                   // after the only barrier: safe

    // ---------- phase 1: pack B1 fragments (loads already landed) ----------
    Frag B1[5];
    B1[0].i.x = cvt_pk_bf16(u0.x, u0.y); B1[0].i.y = cvt_pk_bf16(u0.z, u0.w);
    B1[0].i.z = cvt_pk_bf16(u1.x, u1.y); B1[0].i.w = cvt_pk_bf16(u1.z, u1.w);
    B1[1].i.x = cvt_pk_bf16(u2.x, u2.y); B1[1].i.y = cvt_pk_bf16(u2.z, u2.w);
    B1[1].i.z = cvt_pk_bf16(u3.x, u3.y); B1[1].i.w = cvt_pk_bf16(u3.z, u3.w);
    B1[2].i.x = cvt_pk_bf16(u4.x, u4.y); B1[2].i.y = cvt_pk_bf16(u4.z, u4.w);
    B1[2].i.z = cvt_pk_bf16(u5.x, u5.y); B1[2].i.w = cvt_pk_bf16(u5.z, u5.w);
    B1[3].i.x = cvt_pk_bf16(u6.x, u6.y); B1[3].i.y = cvt_pk_bf16(u6.z, u6.w);
    B1[3].i.z = cvt_pk_bf16(u7.x, u7.y); B1[3].i.w = cvt_pk_bf16(u7.z, u7.w);
    B1[4].i = make_int4(0, 0, 0, 0);
    if (hi == 0) {                         // slots 64..71: coords + bias-1.0
        B1[4].i.x = cvt_pk_bf16(y01.x, y01.y);
        B1[4].i.y = cvt_pk_bf16(yz,    x01.x);
        B1[4].i.z = cvt_pk_bf16(x01.y, xz);
        B1[4].i.w = cvt_pk_bf16(1.0f,  0.0f);   // slot 70 = bias edge value
    }

    const f32x16 z16 = {0.f,0.f,0.f,0.f,0.f,0.f,0.f,0.f,
                        0.f,0.f,0.f,0.f,0.f,0.f,0.f,0.f};

    // ---------- phase 2+3: GEMM1 (Mtile pairs) + packed gelu + score + A2 ---
    Frag A2[8];
    f32x2 scv = {0.f, 0.f};
    #pragma unroll
    for (int p = 0; p < 2; ++p) {
        f32x16 aA = z16, aB = z16;
        #pragma unroll
        for (int ks = 0; ks < 5; ++ks) {
            Frag wa0, wa1;
            wa0.i = sW1[((2 * p + 0) * 5 + ks) * 64 + l];
            wa1.i = sW1[((2 * p + 1) * 5 + ks) * 64 + l];
            aA = __builtin_amdgcn_mfma_f32_32x32x16_bf16(wa0.b, B1[ks].b, aA, 0, 0, 0);
            aB = __builtin_amdgcn_mfma_f32_32x32x16_bf16(wa1.b, B1[ks].b, aB, 0, 0, 0);
        }
        #pragma unroll
        for (int m = 0; m < 2; ++m) {
            const f32x16 ac = m ? aB : aA;
            const int Mt = 2 * p + m;
            const float* avb = sAv + Mt * 32 + hi * 16;
            float4 av0 = *(const float4*)(avb + 0);
            float4 av1 = *(const float4*)(avb + 4);
            float4 av2 = *(const float4*)(avb + 8);
            float4 av3 = *(const float4*)(avb + 12);
            f32x2 avv[8] = {{av0.x, av0.y}, {av0.z, av0.w},
                            {av1.x, av1.y}, {av1.z, av1.w},
                            {av2.x, av2.y}, {av2.z, av2.w},
                            {av3.x, av3.y}, {av3.z, av3.w}};
            unsigned hw[8];
            #pragma unroll
            for (int i = 0; i < 8; ++i) {
                f32x2 vin = {ac[2 * i], ac[2 * i + 1]};
                f32x2 hv = fast_gelu2(vin);
                scv = __builtin_elementwise_fma(hv, avv[i], scv);
                hw[i] = cvt_pk_bf16(hv.x, hv.y);
            }
            A2[2 * Mt + 0].i.x = hw[0];
            A2[2 * Mt + 0].i.y = hw[1];
            A2[2 * Mt + 0].i.z = hw[2];
            A2[2 * Mt + 0].i.w = hw[3];
            A2[2 * Mt + 1].i.x = hw[4];
            A2[2 * Mt + 1].i.y = hw[5];
            A2[2 * Mt + 1].i.z = hw[6];
            A2[2 * Mt + 1].i.w = hw[7];
        }
    }

    // ---- prefetch Nt=0 W2 fragments: LDS latency hides under softmax ----
    Frag wf[8];
    #pragma unroll
    for (int ks2 = 0; ks2 < 8; ++ks2)
        wf[ks2].i = sW2[(0 * 8 + ks2) * 64 + l];

    // ---------- phase 4: softmax (edge el per lane) ----------
    float sc = scv.x + scv.y;
    sc += __shfl_xor(sc, 32, 64);          // sum over lane halves (hidden split)
    float mx = sc;
    mx = fmaxf(mx, __shfl_xor(mx, 1, 64));
    mx = fmaxf(mx, __shfl_xor(mx, 2, 64));
    mx = fmaxf(mx, __shfl_xor(mx, 4, 64));
    mx = fmaxf(mx, __shfl_xor(mx, 8, 64));
    mx = fmaxf(mx, __shfl_xor(mx, 16, 64));
    float ex = __expf(sc - mx);
    float sm = ex;
    sm += __shfl_xor(sm, 1, 64);
    sm += __shfl_xor(sm, 2, 64);
    sm += __shfl_xor(sm, 4, 64);
    sm += __shfl_xor(sm, 8, 64);
    sm += __shfl_xor(sm, 16, 64);
    const float alpha = __fdividef(ex, sm);    // alpha[edge el]

    // ---------- phase 5: GEMM2 (D[edge][out], K=128 over 8 steps) ----------
    // o0 consumes prefetched wf; o1's loads pipeline inside the loop.
    f32x16 o0 = z16, o1 = z16;
    #pragma unroll
    for (int ks2 = 0; ks2 < 8; ++ks2) {
        Frag w1;
        w1.i = sW2[(1 * 8 + ks2) * 64 + l];
        o0 = __builtin_amdgcn_mfma_f32_32x32x16_bf16(A2[ks2].b, wf[ks2].b, o0, 0, 0, 0);
        o1 = __builtin_amdgcn_mfma_f32_32x32x16_bf16(A2[ks2].b, w1.b, o1, 0, 0, 0);
    }

    // ---------- phase 6: alpha-weighted edge reduce + store ----------
    float ar[16];
    #pragma unroll
    for (int r = 0; r < 16; ++r)
        ar[r] = __shfl(alpha, 8 * (r >> 2) + 4 * hi + (r & 3), 64);

    #pragma unroll
    for (int nt = 0; nt < 2; ++nt) {
        const f32x16 oo = nt ? o1 : o0;
        f32x2 acc = {0.f, 0.f};
        #pragma unroll
        for (int i = 0; i < 8; ++i) {
            f32x2 ov = {oo[2 * i], oo[2 * i + 1]};
            f32x2 av2 = {ar[2 * i], ar[2 * i + 1]};
            acc = __builtin_elementwise_fma(ov, av2, acc);
        }
        float o = acc.x + acc.y;
        o += __shfl_xor(o, 32, 64);        // sum the two lane halves' edges
        if (l < 32)
            out[qc * 64 + nt * 32 + l] = o + b2[nt * 32 + l];
    }
}

extern "C" void kernel_launch(void* const* d_in, const int* in_sizes, int n_in,
                              void* d_out, int out_size, void* d_ws, size_t ws_size,
                              hipStream_t stream) {
    const float* y   = (const float*)d_in[0];
    const float* xq  = (const float*)d_in[1];
    const float* f_y = (const float*)d_in[2];
    const float* W1  = (const float*)d_in[3];
    const float* b1  = (const float*)d_in[4];
    const float* W2  = (const float*)d_in[5];
    const float* b2  = (const float*)d_in[6];
    const float* av  = (const float*)d_in[7];
    const int*   nbr = (const int*)d_in[8];
    float* out = (float*)d_out;

    const int n_out = in_sizes[1] / 3;      // x is [n_out][3]

    int4*  W1p = (int4*)d_ws;               // 1280 frags = 20 KB
    int4*  W2p = W1p + 1280;                // 1024 frags = 16 KB
    float* avp = (float*)(W1p + 2304);      // 128 floats

    pack_weights_kernel<<<10, 256, 0, stream>>>(W1, W2, b1, av, W1p, W2p, avp);
    const int nblk = (n_out + WAVES - 1) / WAVES;
    it_mfma_kernel<<<nblk, 512, 0, stream>>>(y, xq, f_y, b2, nbr,
                                             W1p, out, n_out);
}

// Round 19
// 70.655 us; speedup vs baseline: 5.3087x; 1.0006x over previous
//
#include <hip/hip_runtime.h>

typedef __attribute__((ext_vector_type(8)))  short bf16x8;
typedef __attribute__((ext_vector_type(16))) float f32x16;
typedef __attribute__((ext_vector_type(2)))  float f32x2;

#define KNBR 32
#define WAVES 8         // waves per block, one query per wave (512 threads)

union Frag { int4 i; bf16x8 b; };

__device__ __forceinline__ unsigned short f2bf(float f) {
    unsigned u = __float_as_uint(f);
    u += 0x7FFFu + ((u >> 16) & 1u);          // RNE to bf16
    return (unsigned short)(u >> 16);
}

__device__ __forceinline__ unsigned cvt_pk_bf16(float lo, float hi) {
    unsigned r;
    asm("v_cvt_pk_bf16_f32 %0, %1, %2" : "=v"(r) : "v"(lo), "v"(hi));
    return r;
}

// gelu_tanh(v) = v * sigmoid(2*c0*(v + c1 v^3)), 2-wide packed (v_pk_* fp32);
// only exp/rcp are scalar trans ops.
__device__ __forceinline__ f32x2 fast_gelu2(f32x2 v) {
    const f32x2 c1v  = {0.044715f, 0.044715f};
    const f32x2 onev = {1.0f, 1.0f};
    const f32x2 K2v  = {-2.3022081951f, -2.3022081951f};  // -2*sqrt(2/pi)*log2(e)
    f32x2 p = v * __builtin_elementwise_fma(c1v, v * v, onev);
    f32x2 t = K2v * p;
    float e0, e1, r0, r1;
    asm("v_exp_f32 %0, %1" : "=v"(e0) : "v"(t.x));
    asm("v_exp_f32 %0, %1" : "=v"(e1) : "v"(t.y));
    f32x2 ev = {e0, e1};
    f32x2 d = ev + onev;
    asm("v_rcp_f32 %0, %1" : "=v"(r0) : "v"(d.x));
    asm("v_rcp_f32 %0, %1" : "=v"(r1) : "v"(d.y));
    f32x2 rv = {r0, r1};
    return v * rv;
}

// Convert f_y (fp32) -> bf16 once. 3.2 MB result is per-XCD-L2-resident, and
// rows in bf16 are already in B1-fragment byte order (direct int4 loads).
__global__ __launch_bounds__(256) void conv_fy_kernel(
    const float* __restrict__ f_y, int4* __restrict__ fyb, int n8)
{
    const int i = blockIdx.x * 256 + threadIdx.x;   // 8 f32 per thread
    if (i < n8) {
        const float4* s = (const float4*)(f_y + (long)i * 8);
        float4 v0 = s[0], v1 = s[1];
        int4 p;
        p.x = cvt_pk_bf16(v0.x, v0.y);
        p.y = cvt_pk_bf16(v0.z, v0.w);
        p.z = cvt_pk_bf16(v1.x, v1.y);
        p.w = cvt_pk_bf16(v1.z, v1.w);
        fyb[i] = p;
    }
}

// 32x32x16 fragment maps (A: row=l&31, B: col=l&31, k=(l>>5)*8+e per K-step).
// C/D: col=lane&31, row=(reg&3)+8*(reg>>2)+4*(lane>>5)  [verified r15].
// GEMM1 slot map (K padded 70->80): 0..63 f_y; 64..69 coords; 70 BIAS; rest 0.
// GEMM2 slot map = identity on h's C/D register layout.
__global__ __launch_bounds__(256) void pack_weights_kernel(
    const float* __restrict__ W1, const float* __restrict__ W2,
    const float* __restrict__ b1, const float* __restrict__ av,
    int4* __restrict__ W1p, int4* __restrict__ W2p, float* __restrict__ avp)
{
    const int idx = blockIdx.x * 256 + threadIdx.x;
    unsigned short vals[8];
    if (idx < 1280) {                      // W1 A-frags: 20 regions x 64 lanes
        const int a = idx >> 6, l = idx & 63;
        const int Mt = a / 5, ks = a - Mt * 5;
        const int row = Mt * 32 + (l & 31), hi = l >> 5;
        #pragma unroll
        for (int e = 0; e < 8; ++e) {
            const int slot = ks * 16 + hi * 8 + e;
            float f;
            if      (slot < 64)  f = W1[(slot + 6) * 128 + row];
            else if (slot < 70)  f = W1[(slot - 64) * 128 + row];
            else if (slot == 70) f = b1[row];
            else                 f = 0.0f;
            vals[e] = f2bf(f);
        }
        int4 v;
        v.x = vals[0] | (vals[1] << 16); v.y = vals[2] | (vals[3] << 16);
        v.z = vals[4] | (vals[5] << 16); v.w = vals[6] | (vals[7] << 16);
        W1p[idx] = v;
    } else if (idx < 2304) {               // W2 B-frags: 16 regions x 64 lanes
        const int i2 = idx - 1280;
        const int rgn = i2 >> 6, l = i2 & 63;
        const int Nt = rgn >> 3, ks2 = rgn & 7;
        const int col = Nt * 32 + (l & 31), hi = l >> 5;
        #pragma unroll
        for (int e = 0; e < 8; ++e) {
            const int Mt = ks2 >> 1;
            const int t  = 2 * (ks2 & 1) + (e >> 2);
            const int c  = e & 3;
            const int hid = Mt * 32 + 4 * (2 * t + hi) + c;
            vals[e] = f2bf(W2[hid * 64 + col]);
        }
        int4 v;
        v.x = vals[0] | (vals[1] << 16); v.y = vals[2] | (vals[3] << 16);
        v.z = vals[4] | (vals[5] << 16); v.w = vals[6] | (vals[7] << 16);
        W2p[i2] = v;
    } else if (idx < 2432) {               // av repacked into C/D reg order
        const int r_ = idx - 2304;         // [Mt][hi][r]
        const int Mt = r_ >> 5, hi = (r_ >> 4) & 1, r = r_ & 15;
        avp[r_] = av[Mt * 32 + 8 * (r >> 2) + 4 * hi + (r & 3)];
    }
}

__global__ __launch_bounds__(512, 4) void it_mfma_kernel(
    const float* __restrict__ y,     // [n_in][3]
    const float* __restrict__ xq,    // [n_out][3]
    const int4*  __restrict__ fyb,   // [n_in] rows of 64 bf16 (8 int4 each)
    const float* __restrict__ b2,    // [64]
    const int*   __restrict__ nbr,   // [n_out*32]
    const int4*  __restrict__ Wall,  // W1p(1280) ++ W2p(1024) ++ avp(128 f32)
    float*       __restrict__ out,   // [n_out][64]
    int n_out)
{
    __shared__ int4  sW[2304];             // 36 KB: W1 frags then W2 frags
    __shared__ float sAv[128];             // av in C/D register order

    const int tid = threadIdx.x;
    const int w   = tid >> 6;              // wave 0..7
    const int l   = tid & 63;              // lane
    const int el  = l & 31;                // this lane's edge
    const int hi  = l >> 5;                // lane half

    const int q = blockIdx.x * WAVES + w;
    const bool active = (q < n_out);
    const int qc = active ? q : 0;

    // nbr first: its latency hides under the (independent) staging loads
    const int ni = nbr[qc * KNBR + el];

    // ---- stage fragments + av into LDS (issues immediately) ----
    #pragma unroll
    for (int t = 0; t < 5; ++t) {
        const int idx = tid + t * 512;
        if (idx < 2304) sW[idx] = Wall[idx];
    }
    if (tid < 128) sAv[tid] = ((const float*)(Wall + 2304))[tid];

    // ---- bf16 f_y gather issues BEFORE the barrier: 4 direct int4 loads,
    //      L2-resident table, already in fragment byte order ----
    const int4* fb = fyb + (long)ni * 8;   // 64 bf16 = 8 int4 per row
    Frag B1[5];
    B1[0].i = fb[0 + hi];                  // slots 16*ks + 8*hi + e
    B1[1].i = fb[2 + hi];
    B1[2].i = fb[4 + hi];
    B1[3].i = fb[6 + hi];
    float2 y01 = {0.f, 0.f}, x01 = {0.f, 0.f};
    float  yz = 0.f, xz = 0.f;
    if (hi == 0) {
        y01 = *(const float2*)(y + ni * 3);
        yz  = y[ni * 3 + 2];
        x01 = *(const float2*)(xq + qc * 3);
        xz  = xq[qc * 3 + 2];
    }
    __syncthreads();
    const int4* sW1 = sW;                  // region (Mt*5+ks)*64 + lane
    const int4* sW2 = sW + 1280;           // region (Nt*8+ks2)*64 + lane

    if (!active) return;                   // after the only barrier: safe

    // ---------- phase 1 tail: coord/bias fragment ----------
    B1[4].i = make_int4(0, 0, 0, 0);
    if (hi == 0) {                         // slots 64..71: coords + bias-1.0
        B1[4].i.x = cvt_pk_bf16(y01.x, y01.y);
        B1[4].i.y = cvt_pk_bf16(yz,    x01.x);
        B1[4].i.z = cvt_pk_bf16(x01.y, xz);
        B1[4].i.w = cvt_pk_bf16(1.0f,  0.0f);   // slot 70 = bias edge value
    }

    const f32x16 z16 = {0.f,0.f,0.f,0.f,0.f,0.f,0.f,0.f,
                        0.f,0.f,0.f,0.f,0.f,0.f,0.f,0.f};

    // ---------- phase 2+3: GEMM1 (Mtile pairs) + packed gelu + score + A2 ---
    Frag A2[8];
    f32x2 scv = {0.f, 0.f};
    #pragma unroll
    for (int p = 0; p < 2; ++p) {
        f32x16 aA = z16, aB = z16;
        #pragma unroll
        for (int ks = 0; ks < 5; ++ks) {
            Frag wa0, wa1;
            wa0.i = sW1[((2 * p + 0) * 5 + ks) * 64 + l];
            wa1.i = sW1[((2 * p + 1) * 5 + ks) * 64 + l];
            aA = __builtin_amdgcn_mfma_f32_32x32x16_bf16(wa0.b, B1[ks].b, aA, 0, 0, 0);
            aB = __builtin_amdgcn_mfma_f32_32x32x16_bf16(wa1.b, B1[ks].b, aB, 0, 0, 0);
        }
        #pragma unroll
        for (int m = 0; m < 2; ++m) {
            const f32x16 ac = m ? aB : aA;
            const int Mt = 2 * p + m;
            const float* avb = sAv + Mt * 32 + hi * 16;
            float4 av0 = *(const float4*)(avb + 0);
            float4 av1 = *(const float4*)(avb + 4);
            float4 av2 = *(const float4*)(avb + 8);
            float4 av3 = *(const float4*)(avb + 12);
            f32x2 avv[8] = {{av0.x, av0.y}, {av0.z, av0.w},
                            {av1.x, av1.y}, {av1.z, av1.w},
                            {av2.x, av2.y}, {av2.z, av2.w},
                            {av3.x, av3.y}, {av3.z, av3.w}};
            unsigned hw[8];
            #pragma unroll
            for (int i = 0; i < 8; ++i) {
                f32x2 vin = {ac[2 * i], ac[2 * i + 1]};
                f32x2 hv = fast_gelu2(vin);
                scv = __builtin_elementwise_fma(hv, avv[i], scv);
                hw[i] = cvt_pk_bf16(hv.x, hv.y);
            }
            A2[2 * Mt + 0].i.x = hw[0];
            A2[2 * Mt + 0].i.y = hw[1];
            A2[2 * Mt + 0].i.z = hw[2];
            A2[2 * Mt + 0].i.w = hw[3];
            A2[2 * Mt + 1].i.x = hw[4];
            A2[2 * Mt + 1].i.y = hw[5];
            A2[2 * Mt + 1].i.z = hw[6];
            A2[2 * Mt + 1].i.w = hw[7];
        }
    }

    // ---- prefetch Nt=0 W2 fragments: LDS latency hides under softmax ----
    Frag wf[8];
    #pragma unroll
    for (int ks2 = 0; ks2 < 8; ++ks2)
        wf[ks2].i = sW2[(0 * 8 + ks2) * 64 + l];

    // ---------- phase 4: softmax (edge el per lane) ----------
    float sc = scv.x + scv.y;
    sc += __shfl_xor(sc, 32, 64);          // sum over lane halves (hidden split)
    float mx = sc;
    mx = fmaxf(mx, __shfl_xor(mx, 1, 64));
    mx = fmaxf(mx, __shfl_xor(mx, 2, 64));
    mx = fmaxf(mx, __shfl_xor(mx, 4, 64));
    mx = fmaxf(mx, __shfl_xor(mx, 8, 64));
    mx = fmaxf(mx, __shfl_xor(mx, 16, 64));
    float ex = __expf(sc - mx);
    float sm = ex;
    sm += __shfl_xor(sm, 1, 64);
    sm += __shfl_xor(sm, 2, 64);
    sm += __shfl_xor(sm, 4, 64);
    sm += __shfl_xor(sm, 8, 64);
    sm += __shfl_xor(sm, 16, 64);
    const float alpha = __fdividef(ex, sm);    // alpha[edge el]

    // ---------- phase 5: GEMM2 (D[edge][out], K=128 over 8 steps) ----------
    f32x16 o0 = z16, o1 = z16;
    #pragma unroll
    for (int ks2 = 0; ks2 < 8; ++ks2) {
        Frag w1;
        w1.i = sW2[(1 * 8 + ks2) * 64 + l];
        o0 = __builtin_amdgcn_mfma_f32_32x32x16_bf16(A2[ks2].b, wf[ks2].b, o0, 0, 0, 0);
        o1 = __builtin_amdgcn_mfma_f32_32x32x16_bf16(A2[ks2].b, w1.b, o1, 0, 0, 0);
    }

    // ---------- phase 6: alpha-weighted edge reduce + store ----------
    float ar[16];
    #pragma unroll
    for (int r = 0; r < 16; ++r)
        ar[r] = __shfl(alpha, 8 * (r >> 2) + 4 * hi + (r & 3), 64);

    #pragma unroll
    for (int nt = 0; nt < 2; ++nt) {
        const f32x16 oo = nt ? o1 : o0;
        f32x2 acc = {0.f, 0.f};
        #pragma unroll
        for (int i = 0; i < 8; ++i) {
            f32x2 ov = {oo[2 * i], oo[2 * i + 1]};
            f32x2 av2 = {ar[2 * i], ar[2 * i + 1]};
            acc = __builtin_elementwise_fma(ov, av2, acc);
        }
        float o = acc.x + acc.y;
        o += __shfl_xor(o, 32, 64);        // sum the two lane halves' edges
        if (l < 32)
            out[qc * 64 + nt * 32 + l] = o + b2[nt * 32 + l];
    }
}

extern "C" void kernel_launch(void* const* d_in, const int* in_sizes, int n_in,
                              void* d_out, int out_size, void* d_ws, size_t ws_size,
                              hipStream_t stream) {
    const float* y   = (const float*)d_in[0];
    const float* xq  = (const float*)d_in[1];
    const float* f_y = (const float*)d_in[2];
    const float* W1  = (const float*)d_in[3];
    const float* b1  = (const float*)d_in[4];
    const float* W2  = (const float*)d_in[5];
    const float* b2  = (const float*)d_in[6];
    const float* av  = (const float*)d_in[7];
    const int*   nbr = (const int*)d_in[8];
    float* out = (float*)d_out;

    const int n_out = in_sizes[1] / 3;      // x is [n_out][3]
    const int nfy   = in_sizes[2];          // n_in * 64 floats

    int4*  W1p = (int4*)d_ws;               // 1280 frags = 20 KB
    int4*  W2p = W1p + 1280;                // 1024 frags = 16 KB
    float* avp = (float*)(W1p + 2304);      // 128 floats (512 B)
    int4*  fyb = W1p + 2336;                // bf16 f_y: nfy*2 bytes (~3.2 MB)

    pack_weights_kernel<<<10, 256, 0, stream>>>(W1, W2, b1, av, W1p, W2p, avp);
    const int n8 = nfy / 8;                 // int4-granules of bf16 f_y
    conv_fy_kernel<<<(n8 + 255) / 256, 256, 0, stream>>>(f_y, fyb, n8);
    const int nblk = (n_out + WAVES - 1) / WAVES;
    it_mfma_kernel<<<nblk, 512, 0, stream>>>(y, xq, fyb, b2, nbr,
                                             W1p, out, n_out);
}